// Round 6
// baseline (2698.048 us; speedup 1.0000x reference)
//
#include <hip/hip_runtime.h>
#include <math.h>

#define Bsz 512
#define Nn  24
#define Tt  25
// Step pipeline (5 kernels):
//   mix1c:    gates1 = partial1(ypB[512:]) + base1 + v8*W8 ; G-mix ; LSTM1 -> h1 (l2cat[0:128)), c1
//   gemm2ext: [h1|h2] (K=256) x W2ext (O=1024) -> ypB = [gates2-pre | partial1(t+1)]
//   mix2:     G-mix gates2 ; LSTM2 -> h2 (l2cat[128:)), yib=tanh(h2), c2
//   gemmf:    yib (K=128) x Wtf (O=256) -> pbuf = [fc1-pre | fc2-pre]
//   finstep:  G-mix+tanh, heads, G-mix, quaternion, outputs, v8f(t+1)
// Learned: cooperative grid.sync = 4.7x slower (L2 inval per sync). Kernel-count
// fusion alone neutral; the lever is redundant LLC traffic -> 128x128 tiles +
// XCD-pinned grid + W8 de-duplication.

typedef _Float16 f16;
typedef _Float16 f16x8 __attribute__((ext_vector_type(8)));
typedef _Float16 f16x4 __attribute__((ext_vector_type(4)));
typedef float f32x4 __attribute__((ext_vector_type(4)));

// ---------------------------------------------------------------------------
// MFMA fp16 GEMM, per-node block-diagonal, W-as-A orientation, 128x128 tile.
//   Y[b,n,o] = sum_k Act[b,n,k] * W[n,o,k] + bias[n,o]
// 1-D grid of Nn*blocksPerN, XCD-pinned: n = (bid&7) + 8*(bid/(8*bpn)),
// inner = (bid>>3) % bpn; o0 = (inner%otiles)*128; b0 = (inner/otiles)*128.
// 4 waves as 2x2, each wave 64o x 64b = 4x4 frags of 16x16x32.
// ---------------------------------------------------------------------------
__global__ __launch_bounds__(256) void gemm128(
    const f16* __restrict__ Act, const float* __restrict__ Act32, int Ka,
    const f16* __restrict__ W, size_t wstride, int otiles, int bpn,
    const float* __restrict__ bias, int bstride,
    f16* __restrict__ Y, int ystride, int yoff)
{
    const int bid = blockIdx.x;
    const int n     = (bid & 7) + 8 * (bid / (8 * bpn));
    const int inner = (bid >> 3) % bpn;
    const int o0 = (inner % otiles) * 128;
    const int b0 = (inner / otiles) * 128;
    const int tid  = threadIdx.x;
    const int wave = tid >> 6, lane = tid & 63;
    const int wm = (wave >> 1) * 64;
    const int wn = (wave & 1) * 64;
    const int m16 = lane & 15, quad = lane >> 4;

    __shared__ __attribute__((aligned(16))) f16 sW[128][72];
    __shared__ __attribute__((aligned(16))) f16 sB[128][72];

    const f16* Wn = W + (size_t)n * wstride;
    f32x4 acc[4][4] = {};
    const int r = tid >> 3, cc = (tid & 7) * 8;

    for (int k0 = 0; k0 < Ka; k0 += 64) {
        for (int row = r; row < 128; row += 32)
            *(f16x8*)&sW[row][cc] = *(const f16x8*)&Wn[(size_t)(o0 + row) * Ka + k0 + cc];
        if (Act) {
            for (int row = r; row < 128; row += 32)
                *(f16x8*)&sB[row][cc] = *(const f16x8*)&Act[((size_t)(b0 + row) * Nn + n) * Ka + k0 + cc];
        } else {
            for (int row = r; row < 128; row += 32) {
                const float* src = &Act32[((size_t)(b0 + row) * Nn + n) * Ka + k0 + cc];
                f16x8 v;
#pragma unroll
                for (int u = 0; u < 8; u++) v[u] = (f16)src[u];
                *(f16x8*)&sB[row][cc] = v;
            }
        }
        __syncthreads();
#pragma unroll
        for (int kk = 0; kk < 64; kk += 32) {
            f16x8 af[4], bf[4];
#pragma unroll
            for (int i = 0; i < 4; i++)
                af[i] = *(const f16x8*)&sW[wm + i * 16 + m16][kk + quad * 8];
#pragma unroll
            for (int j = 0; j < 4; j++)
                bf[j] = *(const f16x8*)&sB[wn + j * 16 + m16][kk + quad * 8];
#pragma unroll
            for (int i = 0; i < 4; i++)
#pragma unroll
                for (int j = 0; j < 4; j++)
                    acc[i][j] = __builtin_amdgcn_mfma_f32_16x16x32_f16(af[i], bf[j], acc[i][j], 0, 0, 0);
        }
        __syncthreads();
    }
#pragma unroll
    for (int i = 0; i < 4; i++) {
        const int orow = o0 + wm + i * 16 + quad * 4;
        float4 bv = make_float4(0.f, 0.f, 0.f, 0.f);
        if (bias) bv = *(const float4*)&bias[(size_t)n * bstride + orow];
#pragma unroll
        for (int j = 0; j < 4; j++) {
            const int bcol = b0 + wn + j * 16 + m16;
            size_t yi = ((size_t)bcol * Nn + n) * (size_t)ystride + yoff + orow;
            f16x4 o4;
            o4[0] = (f16)(acc[i][j][0] + bv.x);
            o4[1] = (f16)(acc[i][j][1] + bv.y);
            o4[2] = (f16)(acc[i][j][2] + bv.z);
            o4[3] = (f16)(acc[i][j][3] + bv.w);
            *(f16x4*)&Y[yi] = o4;
        }
    }
}

// ---------------------------------------------------------------------------
// Weight prep: Wz (24,512,64)=Wx0[:,:64,:]^T ; W2ext (24,1024,256)=
// [[Wx1|Wh1];[Wh0|0]]^T ; W8 (24,8,512)=Wx0[64:72] ; Wh0t (24,512,128)=Wh0^T
// ---------------------------------------------------------------------------
__global__ __launch_bounds__(256) void prep_w01(
    const float* __restrict__ Wx0, const float* __restrict__ Wh0,
    const float* __restrict__ Wx1, const float* __restrict__ Wh1,
    f16* __restrict__ Wz, f16* __restrict__ W2ext, f16* __restrict__ W8,
    f16* __restrict__ Wh0t)
{
    size_t idx = (size_t)blockIdx.x * 256 + threadIdx.x;
    const size_t nz = (size_t)Nn * 512 * 64;        // 786432
    const size_t n2 = (size_t)Nn * 1024 * 256;      // 6291456
    const size_t n8 = (size_t)Nn * 8 * 512;         // 98304
    const size_t nh = (size_t)Nn * 512 * 128;       // 1572864
    if (idx < nz) {
        int k = idx & 63; int o = (idx >> 6) & 511; int n = (int)(idx >> 15);
        Wz[idx] = (f16)Wx0[((size_t)n * 72 + k) * 512 + o];
    } else if (idx < nz + n2) {
        size_t i3 = idx - nz;
        int k = (int)(i3 & 255);
        size_t no = i3 >> 8;
        int o = (int)(no & 1023); int n = (int)(no >> 10);
        float v;
        if (o < 512) v = (k < 128) ? Wx1[((size_t)n * 128 + k) * 512 + o]
                                   : Wh1[((size_t)n * 128 + (k - 128)) * 512 + o];
        else         v = (k < 128) ? Wh0[((size_t)n * 128 + k) * 512 + (o - 512)] : 0.f;
        W2ext[i3] = (f16)v;
    } else if (idx < nz + n2 + n8) {
        size_t i4 = idx - nz - n2;
        int o = (int)(i4 & 511);
        size_t ko = i4 >> 9;
        int k = (int)(ko & 7); int n = (int)(ko >> 3);
        W8[i4] = (f16)Wx0[((size_t)n * 72 + 64 + k) * 512 + o];
    } else if (idx < nz + n2 + n8 + nh) {
        size_t i5 = idx - nz - n2 - n8;
        int k = (int)(i5 & 127);
        size_t no = i5 >> 7;
        int o = (int)(no & 511); int n = (int)(no >> 9);
        Wh0t[i5] = (f16)Wh0[((size_t)n * 128 + k) * 512 + o];
    }
}

// Wtf (24,256,128): o<128 -> fcW^T, else fc2W^T
__global__ __launch_bounds__(256) void prep_wf(
    const float* __restrict__ fcW, const float* __restrict__ fc2W,
    f16* __restrict__ Wtf)
{
    size_t idx = (size_t)blockIdx.x * 256 + threadIdx.x;
    if (idx >= (size_t)Nn * 256 * 128) return;
    int k = (int)(idx & 127);
    size_t no = idx >> 7;
    int o = (int)(no & 255); int n = (int)(no >> 8);
    float v = (o < 128) ? fcW[((size_t)n * 128 + k) * 128 + o]
                        : fc2W[((size_t)n * 128 + k) * 128 + (o - 128)];
    Wtf[idx] = (f16)v;
}

// Wti (256,256)=[ih1W|ih2W]^T ; bi (256) ; bcat (24,256) ; bcat2 (24,1024)=[b1|0]
__global__ __launch_bounds__(256) void prep_wi(
    const float* __restrict__ ih1W, const float* __restrict__ ih2W,
    const float* __restrict__ ih1b, const float* __restrict__ ih2b,
    const float* __restrict__ fcb, const float* __restrict__ fc2b,
    const float* __restrict__ b1,
    f16* __restrict__ Wti, float* __restrict__ bi, float* __restrict__ bcat,
    float* __restrict__ bcat2)
{
    int idx = blockIdx.x * 256 + threadIdx.x;   // 65536
    int k = idx & 255, o = idx >> 8;
    Wti[idx] = (f16)((o < 128) ? ih1W[(size_t)k * 128 + o] : ih2W[(size_t)k * 128 + (o - 128)]);
    if (idx < 256) bi[idx] = (idx < 128) ? ih1b[idx] : ih2b[idx - 128];
    if (idx < Nn * 256) {
        int n = idx >> 8, oo = idx & 255;
        bcat[idx] = (oo < 128) ? fcb[n * 128 + oo] : fc2b[n * 128 + (oo - 128)];
    }
    if (idx < Nn * 1024) {
        int n = idx >> 10, oo = idx & 1023;
        bcat2[idx] = (oo < 512) ? b1[n * 512 + oo] : 0.f;
    }
}

// v8f(0) = x[:8] per (b,n) ; ls = x[:4]
__global__ __launch_bounds__(256) void init_small(
    const float* __restrict__ x, f16* __restrict__ v8f, float* __restrict__ ls)
{
    size_t idx = (size_t)blockIdx.x * 256 + threadIdx.x;
    if (idx < (size_t)Bsz * Nn * 8) {
        v8f[idx] = (f16)x[idx];
        if ((idx & 7) < 4) {
            size_t bn = idx >> 3;
            ls[bn * 4 + (idx & 3)] = x[idx];
        }
    }
}

// ---------------------------------------------------------------------------
// Init mix: Yhc (B,N,256) f16 = [h-pre|c-pre]; h0 -> h0f + l2cat[128:256);
// c0 -> c1, c2.
// ---------------------------------------------------------------------------
__global__ __launch_bounds__(256) void mix_init(
    const f16* __restrict__ Yhc, const float* __restrict__ G,
    f16* __restrict__ h0f, f16* __restrict__ l2cat,
    float* __restrict__ c1, float* __restrict__ c2)
{
    const int b = blockIdx.x;
    const int tid = threadIdx.x;
    __shared__ float sY[6144], sG[576];
    for (int i = tid; i < 576; i += 256) sG[i] = G[i];
    for (int v = tid; v < 768; v += 256) {
        int c8 = (v & 31) * 8, n = v >> 5;
        f16x8 t = *(const f16x8*)&Yhc[((size_t)b * Nn + n) * 256 + c8];
        float* d = &sY[n * 256 + c8];
#pragma unroll
        for (int u = 0; u < 8; u++) d[u] = (float)t[u];
    }
    __syncthreads();
    for (int w = tid; w < 3072; w += 256) {
        int o = w & 127, m = w >> 7;
        float ah = 0.f, ac = 0.f;
#pragma unroll
        for (int n = 0; n < 24; n++) {
            float g = sG[m * 24 + n];
            ah += g * sY[n * 256 + o];
            ac += g * sY[n * 256 + 128 + o];
        }
        size_t row = (size_t)b * Nn + m;
        f16 hf = (f16)ah;
        h0f[row * 128 + o] = hf;
        l2cat[row * 256 + 128 + o] = hf;
        c1[row * 128 + o] = ac;
        c2[row * 128 + o] = ac;
    }
}

// ---------------------------------------------------------------------------
// mix1c: complete gates1 (partial1 + base1 + v8*W8), G-mix, LSTM1.
// grid = 64 b-groups(8) x 4 j-tiles(32). Outputs h1 -> l2cat[0:128), c1.
// ---------------------------------------------------------------------------
__global__ __launch_bounds__(256) void mix1c(
    const f16* __restrict__ ypB, const f16* __restrict__ base1,
    const f16* __restrict__ W8, const f16* __restrict__ v8f,
    const float* __restrict__ G,
    float* __restrict__ c1, f16* __restrict__ l2cat)
{
    const int bg = blockIdx.x >> 2;
    const int jt = (blockIdx.x & 3) * 32;
    const int b0 = bg * 8;
    const int tid = threadIdx.x;
    __shared__ __attribute__((aligned(16))) f16 sYc[8][24][136]; // cols: g*32+jj
    __shared__ float sG[576];
    __shared__ __attribute__((aligned(16))) f16 sV8[8][24][8];
    for (int i = tid; i < 576; i += 256) sG[i] = G[i];
    for (int i = tid; i < 192; i += 256) {
        int bb = i / 24, n = i - bb * 24;
        *(f16x8*)&sV8[bb][n][0] = *(const f16x8*)&v8f[((size_t)(b0 + bb) * Nn + n) * 8];
    }
    __syncthreads();
    // completion: 8b x 24n x 16 chunks of f16x8
    for (int i = tid; i < 3072; i += 256) {
        const int c8 = (i & 15) * 8;
        const int n  = (i >> 4) % 24;
        const int bb = (i >> 4) / 24;
        const int g = c8 >> 5;
        const int o8 = g * 128 + jt + (c8 & 31);
        const size_t rowb = (size_t)(b0 + bb) * Nn + n;
        f16x8 pp = *(const f16x8*)&ypB[rowb * 1024 + 512 + o8];
        f16x8 bs = *(const f16x8*)&base1[rowb * 512 + o8];
        float acc[8];
#pragma unroll
        for (int u = 0; u < 8; u++) acc[u] = (float)pp[u] + (float)bs[u];
#pragma unroll
        for (int k = 0; k < 8; k++) {
            float v = (float)sV8[bb][n][k];
            f16x8 ww = *(const f16x8*)&W8[((size_t)n * 8 + k) * 512 + o8];
#pragma unroll
            for (int u = 0; u < 8; u++) acc[u] += v * (float)ww[u];
        }
        f16x8 oo;
#pragma unroll
        for (int u = 0; u < 8; u++) oo[u] = (f16)acc[u];
        *(f16x8*)&sYc[bb][n][c8] = oo;
    }
    __syncthreads();
    // mix + LSTM: 8b x 24m x 8 j4-groups
    for (int w = tid; w < 1536; w += 256) {
        const int j4 = (w & 7) * 4;
        const int m  = (w >> 3) % 24;
        const int bb = (w >> 3) / 24;
        float gi[4] = {}, gf[4] = {}, gg[4] = {}, go[4] = {};
        const float* gr = &sG[m * 24];
#pragma unroll
        for (int n = 0; n < 24; n++) {
            float g = gr[n];
            const f16* yn = &sYc[bb][n][0];
            f16x4 vi = *(const f16x4*)&yn[j4];
            f16x4 vf = *(const f16x4*)&yn[32 + j4];
            f16x4 vg = *(const f16x4*)&yn[64 + j4];
            f16x4 vo = *(const f16x4*)&yn[96 + j4];
#pragma unroll
            for (int u = 0; u < 4; u++) {
                gi[u] += g * (float)vi[u];
                gf[u] += g * (float)vf[u];
                gg[u] += g * (float)vg[u];
                go[u] += g * (float)vo[u];
            }
        }
        const size_t row = (size_t)(b0 + bb) * Nn + m;
        const int col = jt + j4;
        float cv[4];
        *(float4*)cv = *(const float4*)&c1[row * 128 + col];
        f16x4 ha;
#pragma unroll
        for (int u = 0; u < 4; u++) {
            float si = 1.f / (1.f + expf(-gi[u]));
            float sf = 1.f / (1.f + expf(-gf[u]));
            float so = 1.f / (1.f + expf(-go[u]));
            float cn = sf * cv[u] + si * tanhf(gg[u]);
            cv[u] = cn;
            ha[u] = (f16)(so * tanhf(cn));
        }
        *(float4*)&c1[row * 128 + col] = *(float4*)cv;
        *(f16x4*)&l2cat[row * 256 + col] = ha;
    }
}

// ---------------------------------------------------------------------------
// mix2: G-mix gates2 (ypB[0:512), stride 1024) + LSTM2, one block per b.
// h2 -> l2cat[128:), tanh(h2) -> yib.
// ---------------------------------------------------------------------------
__global__ __launch_bounds__(256) void mix2(
    const f16* __restrict__ ypB, const float* __restrict__ G,
    float* __restrict__ c,
    f16* __restrict__ dstA, f16* __restrict__ dstB)
{
    const int b = blockIdx.x;
    const int tid = threadIdx.x;
    __shared__ __attribute__((aligned(16))) f16 sY[12288];  // 24 x 512
    __shared__ float sG[576];
    for (int i = tid; i < 576; i += 256) sG[i] = G[i];
    for (int i = tid; i < 1536; i += 256) {
        int n = i >> 6, c8 = (i & 63) * 8;
        *(f16x8*)&sY[n * 512 + c8] = *(const f16x8*)&ypB[((size_t)b * Nn + n) * 1024 + c8];
    }
    __syncthreads();
    for (int w = tid; w < 768; w += 256) {
        const int m = w >> 5, j4 = (w & 31) * 4;
        float gi[4] = {}, gf[4] = {}, gg[4] = {}, go[4] = {};
        const float* gr = &sG[m * 24];
#pragma unroll
        for (int n = 0; n < 24; n++) {
            float g = gr[n];
            const f16* yn = &sY[n * 512];
            f16x4 vi = *(const f16x4*)&yn[j4];
            f16x4 vf = *(const f16x4*)&yn[128 + j4];
            f16x4 vg = *(const f16x4*)&yn[256 + j4];
            f16x4 vo = *(const f16x4*)&yn[384 + j4];
#pragma unroll
            for (int u = 0; u < 4; u++) {
                gi[u] += g * (float)vi[u];
                gf[u] += g * (float)vf[u];
                gg[u] += g * (float)vg[u];
                go[u] += g * (float)vo[u];
            }
        }
        const size_t row = (size_t)b * Nn + m;
        float cv[4];
        *(float4*)cv = *(const float4*)&c[row * 128 + j4];
        f16x4 ha, hb;
#pragma unroll
        for (int u = 0; u < 4; u++) {
            float si = 1.f / (1.f + expf(-gi[u]));
            float sf = 1.f / (1.f + expf(-gf[u]));
            float so = 1.f / (1.f + expf(-go[u]));
            float cn = sf * cv[u] + si * tanhf(gg[u]);
            cv[u] = cn;
            float h = so * tanhf(cn);
            ha[u] = (f16)h;
            hb[u] = (f16)tanhf(h);
        }
        *(float4*)&c[row * 128 + j4] = *(float4*)cv;
        *(f16x4*)&dstA[row * 256 + 128 + j4] = ha;
        *(f16x4*)&dstB[row * 128 + j4] = hb;
    }
}

// ---------------------------------------------------------------------------
// finstep: fc-mix + tanh, heads, second mix, quaternion, outputs, v8f(t+1).
// One block per b.
// ---------------------------------------------------------------------------
__global__ __launch_bounds__(256) void finstep(
    const f16* __restrict__ p, const float* __restrict__ G,
    const float* __restrict__ locW, const float* __restrict__ locb,
    const float* __restrict__ lzW, const float* __restrict__ lzb,
    float* __restrict__ ls, f16* __restrict__ v8f,
    float* __restrict__ out, int t)
{
    const int b = blockIdx.x;
    const int tid = threadIdx.x;
    __shared__ __attribute__((aligned(16))) f16 sP[6144];
    __shared__ __attribute__((aligned(16))) f16 sY1[3072], sY2[3072];
    __shared__ float sG[576];
    __shared__ float sLp[24][3], sZp[24][4], sL3[24][3], sZ3[24][4];
    for (int i = tid; i < 576; i += 256) sG[i] = G[i];
    for (int i = tid; i < 768; i += 256) {
        int n = i >> 5, c8 = (i & 31) * 8;
        *(f16x8*)&sP[n * 256 + c8] = *(const f16x8*)&p[((size_t)b * Nn + n) * 256 + c8];
    }
    __syncthreads();
    for (int w = tid; w < 768; w += 256) {
        const int m = w >> 5, o4 = (w & 31) * 4;
        float a1[4] = {}, a2[4] = {};
        const float* gr = &sG[m * 24];
#pragma unroll
        for (int n = 0; n < 24; n++) {
            float g = gr[n];
            f16x4 p1 = *(const f16x4*)&sP[n * 256 + o4];
            f16x4 p2 = *(const f16x4*)&sP[n * 256 + 128 + o4];
#pragma unroll
            for (int u = 0; u < 4; u++) { a1[u] += g * (float)p1[u]; a2[u] += g * (float)p2[u]; }
        }
        f16x4 y1, y2;
#pragma unroll
        for (int u = 0; u < 4; u++) { y1[u] = (f16)tanhf(a1[u]); y2[u] = (f16)tanhf(a2[u]); }
        *(f16x4*)&sY1[m * 128 + o4] = y1;
        *(f16x4*)&sY2[m * 128 + o4] = y2;
    }
    __syncthreads();
    if (tid < 72) {
        int m = tid / 3, j = tid - m * 3;
        float s = locb[j];
        for (int o = 0; o < 128; o++) s += (float)sY1[m * 128 + o] * locW[o * 3 + j];
        sLp[m][j] = s;
    } else if (tid < 168) {
        int w2 = tid - 72; int m = w2 >> 2, j = w2 & 3;
        float s = lzb[j];
        for (int o = 0; o < 128; o++) s += (float)sY2[m * 128 + o] * lzW[o * 4 + j];
        sZp[m][j] = s;
    }
    __syncthreads();
    if (tid < 72) {
        int m = tid / 3, j = tid - m * 3;
        float s = 0.f;
#pragma unroll
        for (int n = 0; n < 24; n++) s += sG[m * 24 + n] * sLp[n][j];
        sL3[m][j] = s;
    } else if (tid < 168) {
        int w2 = tid - 72; int m = w2 >> 2, j = w2 & 3;
        float s = 0.f;
#pragma unroll
        for (int n = 0; n < 24; n++) s += sG[m * 24 + n] * sZp[n][j];
        sZ3[m][j] = s;
    }
    __syncthreads();
    if (tid < 24) {
        const int m = tid;
        float xx = sL3[m][0], xy = sL3[m][1], xz = sL3[m][2];
        float r = rsqrtf(1.f + xx * xx + xy * xy + xz * xz);
        float dw = r, dx = xx * r, dy = xy * r, dz = xz * r;
        size_t li = ((size_t)b * Nn + m) * 4;
        float qw = ls[li], qx = ls[li + 1], qy = ls[li + 2], qz = ls[li + 3];
        float lw = qw * dw - qx * dx - qy * dy - qz * dz;
        float lx = qw * dx + qx * dw + qy * dz - qz * dy;
        float ly = qw * dy - qx * dz + qy * dw + qz * dx;
        float lz = qw * dz + qx * dy - qy * dx + qz * dw;
        size_t oi = (((size_t)b * Tt + t) * Nn + m) * 4;
        out[oi + 0] = lw; out[oi + 1] = lx; out[oi + 2] = ly; out[oi + 3] = lz;
        size_t zi = (size_t)Bsz * Tt * Nn * 4 + oi;
        out[zi + 0] = sZ3[m][0]; out[zi + 1] = sZ3[m][1];
        out[zi + 2] = sZ3[m][2]; out[zi + 3] = sZ3[m][3];
        ls[li] = lw; ls[li + 1] = lx; ls[li + 2] = ly; ls[li + 3] = lz;
        f16x8 v8;
        v8[0] = (f16)lw; v8[1] = (f16)lx; v8[2] = (f16)ly; v8[3] = (f16)lz;
        v8[4] = (f16)dw; v8[5] = (f16)dx; v8[6] = (f16)dy; v8[7] = (f16)dz;
        *(f16x8*)&v8f[((size_t)b * Nn + m) * 8] = v8;
    }
}

extern "C" void kernel_launch(void* const* d_in, const int* in_sizes, int n_in,
                              void* d_out, int out_size, void* d_ws, size_t ws_size,
                              hipStream_t stream)
{
    const float* x    = (const float*)d_in[0];
    const float* enc  = (const float*)d_in[1];
    const float* z    = (const float*)d_in[2];
    const float* G    = (const float*)d_in[4];
    const float* Wx0  = (const float*)d_in[5];
    const float* Wh0  = (const float*)d_in[6];
    const float* b0i  = (const float*)d_in[7];
    const float* Wx1  = (const float*)d_in[8];
    const float* Wh1  = (const float*)d_in[9];
    const float* b1i  = (const float*)d_in[10];
    const float* fcW  = (const float*)d_in[11];
    const float* fcb  = (const float*)d_in[12];
    const float* fc2W = (const float*)d_in[13];
    const float* fc2b = (const float*)d_in[14];
    const float* ih1W = (const float*)d_in[15];
    const float* ih1b = (const float*)d_in[16];
    const float* ih2W = (const float*)d_in[17];
    const float* ih2b = (const float*)d_in[18];
    const float* locW = (const float*)d_in[19];
    const float* locb = (const float*)d_in[20];
    const float* lzW  = (const float*)d_in[21];
    const float* lzb  = (const float*)d_in[22];
    float* out = (float*)d_out;

    const size_t BN = (size_t)Bsz * Nn;
    char* wp = (char*)d_ws;
    size_t off = 0;
    auto carve = [&](size_t bytes) -> char* {
        char* pc = wp + off;
        off += (bytes + 255) & ~(size_t)255;
        return pc;
    };
    f16*   Wz     = (f16*)carve((size_t)Nn * 512 * 64 * 2);
    f16*   W2ext  = (f16*)carve((size_t)Nn * 1024 * 256 * 2);
    f16*   W8     = (f16*)carve((size_t)Nn * 8 * 512 * 2);
    f16*   Wh0t   = (f16*)carve((size_t)Nn * 512 * 128 * 2);
    f16*   Wtf    = (f16*)carve((size_t)Nn * 256 * 128 * 2);
    f16*   Wti    = (f16*)carve((size_t)256 * 256 * 2);
    float* bcat   = (float*)carve((size_t)Nn * 256 * 4);
    float* bcat2  = (float*)carve((size_t)Nn * 1024 * 4);
    float* bi     = (float*)carve(256 * 4);
    f16*   base1  = (f16*)carve(BN * 512 * 2);
    f16*   l2cat  = (f16*)carve(BN * 256 * 2);
    f16*   yib    = (f16*)carve(BN * 128 * 2);
    f16*   h0f    = (f16*)carve(BN * 128 * 2);
    float* c1     = (float*)carve(BN * 128 * 4);
    float* c2     = (float*)carve(BN * 128 * 4);
    float* ls     = (float*)carve(BN * 4 * 4);
    f16*   v8f    = (f16*)carve(BN * 8 * 2);
    f16*   ypB    = (f16*)carve(BN * 1024 * 2);
    f16*   yp0    = (f16*)carve(BN * 256 * 2);
    f16*   pbuf   = (f16*)carve(BN * 256 * 2);

    // ---- one-time prep ----
    prep_w01<<<34176, 256, 0, stream>>>(Wx0, Wh0, Wx1, Wh1, Wz, W2ext, W8, Wh0t);
    prep_wf<<<3072, 256, 0, stream>>>(fcW, fc2W, Wtf);
    prep_wi<<<256, 256, 0, stream>>>(ih1W, ih2W, ih1b, ih2b, fcb, fc2b, b1i,
                                     Wti, bi, bcat, bcat2);
    init_small<<<384, 256, 0, stream>>>(x, v8f, ls);

    // base1 = z.Wz + b0 (constant over all steps). O=512 -> bpn=16, grid 384.
    gemm128<<<384, 256, 0, stream>>>(nullptr, z, 64, Wz, (size_t)512 * 64, 4, 16,
                                     b0i, 512, base1, 512, 0);
    // [h0|c0]pre from enc: O=256 -> bpn=8, grid 192.
    gemm128<<<192, 256, 0, stream>>>(nullptr, enc, 256, Wti, 0, 2, 8,
                                     bi, 0, yp0, 256, 0);
    mix_init<<<512, 256, 0, stream>>>(yp0, G, h0f, l2cat, c1, c2);
    // partial1(0) = h0.Wh0 -> ypB[...,512:1024). O=512 -> bpn=16, grid 384.
    gemm128<<<384, 256, 0, stream>>>(h0f, nullptr, 128, Wh0t, (size_t)512 * 128, 4, 16,
                                     nullptr, 0, ypB, 1024, 512);

    // ---- T sequential steps: 5 kernels each ----
    for (int t = 0; t < Tt; t++) {
        mix1c<<<256, 256, 0, stream>>>(ypB, base1, W8, v8f, G, c1, l2cat);
        // gemm2ext: O=1024 -> otiles=8, bpn=32, grid 768.
        gemm128<<<768, 256, 0, stream>>>(l2cat, nullptr, 256, W2ext, (size_t)1024 * 256,
                                         8, 32, bcat2, 1024, ypB, 1024, 0);
        mix2<<<512, 256, 0, stream>>>(ypB, G, c2, l2cat, yib);
        // gemmf: O=256 -> otiles=2, bpn=8, grid 192.
        gemm128<<<192, 256, 0, stream>>>(yib, nullptr, 128, Wtf, (size_t)256 * 128,
                                         2, 8, bcat, 256, pbuf, 256, 0);
        finstep<<<512, 256, 0, stream>>>(pbuf, G, locW, locb, lzW, lzb, ls, v8f, out, t);
    }
}

// Round 7
// 2677.457 us; speedup vs baseline: 1.0077x; 1.0077x over previous
//
#include <hip/hip_runtime.h>
#include <math.h>

#define Bsz 512
#define Nn  24
#define Tt  25
// Step pipeline (5 kernels/step):
//   mix1c: gates1(t) = ypB[512:] (h1(t-1)Wh0 + zWz + b0, from prev gemm2ext) + v8(t)*W8;
//          G-mix; LSTM1 -> h1 -> l2cat[0:128), c1
//   gemm2ext: l2cat=[h1|h2|z] (K=320) x W2ext (O=1024) -> ypB=[gates2pre | gates1pre(t+1)-v8term]
//   mix2: G-mix ypB[0:512); LSTM2 -> h2 -> l2cat[128:256), yib=tanh(h2), c2
//   gemmf: yib (K=128) x Wtf (O=256) -> pbuf
//   finstep: fc-mix+tanh, heads, 2nd mix, quaternion, out, v8f(t+1)
// Learned: coop grid.sync 4.7x slower (L2 inval); kernel fusion & traffic shuffles
// neutral (R3/R5/R6 all ~2500-2700): working set is L2/LLC resident; cost is
// dispatch overhead + small-kernel walls. This round: z-fold (kills base1) + tiled prep.

typedef _Float16 f16;
typedef _Float16 f16x8 __attribute__((ext_vector_type(8)));
typedef _Float16 f16x4 __attribute__((ext_vector_type(4)));
typedef float f32x4 __attribute__((ext_vector_type(4)));

// ---------------------------------------------------------------------------
// MFMA fp16 GEMM, per-node block-diagonal, W-as-A orientation, 128x128 tile.
// Y[b,n,obase+o] = sum_k Act[b,n,k]*W[n,obase+o,k] + bias[n,obase+o]
// 1-D XCD-pinned grid: n=(bid&7)+8*(bid/(8*bpn)); inner=(bid>>3)%bpn;
// o0=obase+(inner%otiles)*128; b0=(inner/otiles)*128.
// ---------------------------------------------------------------------------
__global__ __launch_bounds__(256) void gemm128(
    const f16* __restrict__ Act, const float* __restrict__ Act32, int Ka,
    const f16* __restrict__ W, size_t wstride, int otiles, int bpn, int obase,
    const float* __restrict__ bias, int bstride,
    f16* __restrict__ Y, int ystride)
{
    const int bid = blockIdx.x;
    const int n     = (bid & 7) + 8 * (bid / (8 * bpn));
    const int inner = (bid >> 3) % bpn;
    const int o0 = obase + (inner % otiles) * 128;
    const int b0 = (inner / otiles) * 128;
    const int tid  = threadIdx.x;
    const int wave = tid >> 6, lane = tid & 63;
    const int wm = (wave >> 1) * 64;
    const int wn = (wave & 1) * 64;
    const int m16 = lane & 15, quad = lane >> 4;

    __shared__ __attribute__((aligned(16))) f16 sW[128][72];
    __shared__ __attribute__((aligned(16))) f16 sB[128][72];

    const f16* Wn = W + (size_t)n * wstride;
    f32x4 acc[4][4] = {};
    const int r = tid >> 3, cc = (tid & 7) * 8;

    for (int k0 = 0; k0 < Ka; k0 += 64) {
        for (int row = r; row < 128; row += 32)
            *(f16x8*)&sW[row][cc] = *(const f16x8*)&Wn[(size_t)(o0 + row) * Ka + k0 + cc];
        if (Act) {
            for (int row = r; row < 128; row += 32)
                *(f16x8*)&sB[row][cc] = *(const f16x8*)&Act[((size_t)(b0 + row) * Nn + n) * Ka + k0 + cc];
        } else {
            for (int row = r; row < 128; row += 32) {
                const float* src = &Act32[((size_t)(b0 + row) * Nn + n) * Ka + k0 + cc];
                f16x8 v;
#pragma unroll
                for (int u = 0; u < 8; u++) v[u] = (f16)src[u];
                *(f16x8*)&sB[row][cc] = v;
            }
        }
        __syncthreads();
#pragma unroll
        for (int kk = 0; kk < 64; kk += 32) {
            f16x8 af[4], bf[4];
#pragma unroll
            for (int i = 0; i < 4; i++)
                af[i] = *(const f16x8*)&sW[wm + i * 16 + m16][kk + quad * 8];
#pragma unroll
            for (int j = 0; j < 4; j++)
                bf[j] = *(const f16x8*)&sB[wn + j * 16 + m16][kk + quad * 8];
#pragma unroll
            for (int i = 0; i < 4; i++)
#pragma unroll
                for (int j = 0; j < 4; j++)
                    acc[i][j] = __builtin_amdgcn_mfma_f32_16x16x32_f16(af[i], bf[j], acc[i][j], 0, 0, 0);
        }
        __syncthreads();
    }
#pragma unroll
    for (int i = 0; i < 4; i++) {
        const int orow = o0 + wm + i * 16 + quad * 4;
        float4 bv = *(const float4*)&bias[(size_t)n * bstride + orow];
#pragma unroll
        for (int j = 0; j < 4; j++) {
            const int bcol = b0 + wn + j * 16 + m16;
            size_t yi = ((size_t)bcol * Nn + n) * (size_t)ystride + orow;
            f16x4 o4;
            o4[0] = (f16)(acc[i][j][0] + bv.x);
            o4[1] = (f16)(acc[i][j][1] + bv.y);
            o4[2] = (f16)(acc[i][j][2] + bv.z);
            o4[3] = (f16)(acc[i][j][3] + bv.w);
            *(f16x4*)&Y[yi] = o4;
        }
    }
}

// ---------------------------------------------------------------------------
// Tiled-transpose prep for W2ext (24,1024,320):
//   o<512:  k<128 -> Wx1[n][k][o]; k<256 -> Wh1[n][k-128][o]; else 0
//   o>=512: k<128 -> Wh0[n][k][o-512]; k<256 -> 0; k<320 -> Wx0[n][k-256][o-512]
// Sources are o-contiguous; dest is k-contiguous -> 64x64 LDS tile transpose.
// grid = 24n x 16 otiles x 5 ktiles = 1920 blocks.
// ---------------------------------------------------------------------------
__global__ __launch_bounds__(256) void prep_w2ext(
    const float* __restrict__ Wx0, const float* __restrict__ Wh0,
    const float* __restrict__ Wx1, const float* __restrict__ Wh1,
    f16* __restrict__ W2ext)
{
    const int bid = blockIdx.x;
    const int kt = bid % 5, ot = (bid / 5) % 16, n = bid / 80;
    const int k0 = kt * 64, o0 = ot * 64;
    const int tid = threadIdx.x;
    __shared__ f16 sT[64][72];
    const int tc = tid & 63, tr = tid >> 6;   // col (contig), row-group
#pragma unroll
    for (int i = 0; i < 16; i++) {
        const int kk = k0 + i * 4 + tr;
        const int oo = o0 + tc;
        float v = 0.f;
        if (oo < 512) {
            if (kk < 128)      v = Wx1[((size_t)n * 128 + kk) * 512 + oo];
            else if (kk < 256) v = Wh1[((size_t)n * 128 + (kk - 128)) * 512 + oo];
        } else {
            if (kk < 128)      v = Wh0[((size_t)n * 128 + kk) * 512 + (oo - 512)];
            else if (kk >= 256) v = Wx0[((size_t)n * 72 + (kk - 256)) * 512 + (oo - 512)];
        }
        sT[i * 4 + tr][tc] = (f16)v;
    }
    __syncthreads();
#pragma unroll
    for (int i = 0; i < 16; i++) {
        const int oo = i * 4 + tr;
        W2ext[((size_t)n * 1024 + o0 + oo) * 320 + k0 + tc] = sT[tc][oo];
    }
}

// Wtf (24,256,128): o<128 -> fcW^T, else fc2W^T. grid 24 x 4ot x 2kt = 192.
__global__ __launch_bounds__(256) void prep_wtf(
    const float* __restrict__ fcW, const float* __restrict__ fc2W,
    f16* __restrict__ Wtf)
{
    const int bid = blockIdx.x;
    const int kt = bid & 1, ot = (bid >> 1) & 3, n = bid >> 3;
    const int k0 = kt * 64, o0 = ot * 64;
    const int tid = threadIdx.x;
    __shared__ f16 sT[64][72];
    const int tc = tid & 63, tr = tid >> 6;
#pragma unroll
    for (int i = 0; i < 16; i++) {
        const int kk = k0 + i * 4 + tr, oo = o0 + tc;
        float v = (oo < 128) ? fcW[((size_t)n * 128 + kk) * 128 + oo]
                             : fc2W[((size_t)n * 128 + kk) * 128 + (oo - 128)];
        sT[i * 4 + tr][tc] = (f16)v;
    }
    __syncthreads();
#pragma unroll
    for (int i = 0; i < 16; i++) {
        const int oo = i * 4 + tr;
        Wtf[((size_t)n * 256 + o0 + oo) * 128 + k0 + tc] = sT[tc][oo];
    }
}

// W8 (24,8,512)=Wx0[64:72] (o contig both sides); Wti (256,256)=[ih1W|ih2W]^T;
// bi(256); bcat(24,256); bcat2(24,1024)=[b1|b0]
__global__ __launch_bounds__(256) void prep_small(
    const float* __restrict__ Wx0,
    const float* __restrict__ ih1W, const float* __restrict__ ih2W,
    const float* __restrict__ ih1b, const float* __restrict__ ih2b,
    const float* __restrict__ fcb, const float* __restrict__ fc2b,
    const float* __restrict__ b0w, const float* __restrict__ b1w,
    f16* __restrict__ W8, f16* __restrict__ Wti,
    float* __restrict__ bi, float* __restrict__ bcat, float* __restrict__ bcat2)
{
    int idx = blockIdx.x * 256 + threadIdx.x;   // 98304
    if (idx < Nn * 8 * 512) {
        int o = idx & 511; int ko = idx >> 9;
        int k = ko & 7, n = ko >> 3;
        W8[idx] = (f16)Wx0[((size_t)n * 72 + 64 + k) * 512 + o];
    }
    if (idx < 65536) {
        int k = idx & 255, o = idx >> 8;
        Wti[idx] = (f16)((o < 128) ? ih1W[(size_t)k * 128 + o] : ih2W[(size_t)k * 128 + (o - 128)]);
    }
    if (idx < 256) bi[idx] = (idx < 128) ? ih1b[idx] : ih2b[idx - 128];
    if (idx < Nn * 256) {
        int n = idx >> 8, oo = idx & 255;
        bcat[idx] = (oo < 128) ? fcb[n * 128 + oo] : fc2b[n * 128 + (oo - 128)];
    }
    if (idx < Nn * 1024) {
        int n = idx >> 10, oo = idx & 1023;
        bcat2[idx] = (oo < 512) ? b1w[n * 512 + oo] : b0w[n * 512 + (oo - 512)];
    }
}

// z -> l2cat[:,256:320); v8f(0)=x[:8]; ls=x[:4]
__global__ __launch_bounds__(256) void init_zl(
    const float* __restrict__ x, const float* __restrict__ z,
    f16* __restrict__ l2cat, f16* __restrict__ v8f, float* __restrict__ ls)
{
    size_t idx = (size_t)blockIdx.x * 256 + threadIdx.x;
    if (idx < (size_t)Bsz * Nn * 64) {
        size_t bn = idx >> 6;
        int j = (int)(idx & 63);
        l2cat[bn * 320 + 256 + j] = (f16)z[bn * 64 + j];
    }
    if (idx < (size_t)Bsz * Nn * 8) {
        v8f[idx] = (f16)x[idx];
        if ((idx & 7) < 4) {
            size_t bn = idx >> 3;
            ls[bn * 4 + (idx & 3)] = x[idx];
        }
    }
}

// Init mix: Yhc (B,N,256) f16 = [h-pre|c-pre]; h0 -> l2cat[0:128) AND [128:256);
// c0 -> c1, c2.
__global__ __launch_bounds__(256) void mix_init(
    const f16* __restrict__ Yhc, const float* __restrict__ G,
    f16* __restrict__ l2cat, float* __restrict__ c1, float* __restrict__ c2)
{
    const int b = blockIdx.x;
    const int tid = threadIdx.x;
    __shared__ float sY[6144], sG[576];
    for (int i = tid; i < 576; i += 256) sG[i] = G[i];
    for (int v = tid; v < 768; v += 256) {
        int c8 = (v & 31) * 8, n = v >> 5;
        f16x8 t = *(const f16x8*)&Yhc[((size_t)b * Nn + n) * 256 + c8];
        float* d = &sY[n * 256 + c8];
#pragma unroll
        for (int u = 0; u < 8; u++) d[u] = (float)t[u];
    }
    __syncthreads();
    for (int w = tid; w < 3072; w += 256) {
        int o = w & 127, m = w >> 7;
        float ah = 0.f, ac = 0.f;
#pragma unroll
        for (int n = 0; n < 24; n++) {
            float g = sG[m * 24 + n];
            ah += g * sY[n * 256 + o];
            ac += g * sY[n * 256 + 128 + o];
        }
        size_t row = (size_t)b * Nn + m;
        f16 hf = (f16)ah;
        l2cat[row * 320 + o] = hf;
        l2cat[row * 320 + 128 + o] = hf;
        c1[row * 128 + o] = ac;
        c2[row * 128 + o] = ac;
    }
}

// ---------------------------------------------------------------------------
// mix1c: gates1 = ypB[512:] + v8*W8; G-mix; LSTM1 -> l2cat[0:128), c1.
// grid = 64 b-groups(8) x 4 j-tiles(32).
// ---------------------------------------------------------------------------
__global__ __launch_bounds__(256) void mix1c(
    const f16* __restrict__ ypB, const f16* __restrict__ W8,
    const f16* __restrict__ v8f, const float* __restrict__ G,
    float* __restrict__ c1, f16* __restrict__ l2cat)
{
    const int bg = blockIdx.x >> 2;
    const int jt = (blockIdx.x & 3) * 32;
    const int b0 = bg * 8;
    const int tid = threadIdx.x;
    __shared__ __attribute__((aligned(16))) f16 sYc[8][24][136]; // cols: g*32+jj
    __shared__ float sG[576];
    __shared__ __attribute__((aligned(16))) f16 sV8[8][24][8];
    for (int i = tid; i < 576; i += 256) sG[i] = G[i];
    for (int i = tid; i < 192; i += 256) {
        int bb = i / 24, n = i - bb * 24;
        *(f16x8*)&sV8[bb][n][0] = *(const f16x8*)&v8f[((size_t)(b0 + bb) * Nn + n) * 8];
    }
    __syncthreads();
    for (int i = tid; i < 3072; i += 256) {
        const int c8 = (i & 15) * 8;
        const int n  = (i >> 4) % 24;
        const int bb = (i >> 4) / 24;
        const int g = c8 >> 5;
        const int o8 = g * 128 + jt + (c8 & 31);
        const size_t rowb = (size_t)(b0 + bb) * Nn + n;
        f16x8 pp = *(const f16x8*)&ypB[rowb * 1024 + 512 + o8];
        float acc[8];
#pragma unroll
        for (int u = 0; u < 8; u++) acc[u] = (float)pp[u];
#pragma unroll
        for (int k = 0; k < 8; k++) {
            float v = (float)sV8[bb][n][k];
            f16x8 ww = *(const f16x8*)&W8[((size_t)n * 8 + k) * 512 + o8];
#pragma unroll
            for (int u = 0; u < 8; u++) acc[u] += v * (float)ww[u];
        }
        f16x8 oo;
#pragma unroll
        for (int u = 0; u < 8; u++) oo[u] = (f16)acc[u];
        *(f16x8*)&sYc[bb][n][c8] = oo;
    }
    __syncthreads();
    for (int w = tid; w < 1536; w += 256) {
        const int j4 = (w & 7) * 4;
        const int m  = (w >> 3) % 24;
        const int bb = (w >> 3) / 24;
        float gi[4] = {}, gf[4] = {}, gg[4] = {}, go[4] = {};
        const float* gr = &sG[m * 24];
#pragma unroll
        for (int n = 0; n < 24; n++) {
            float g = gr[n];
            const f16* yn = &sYc[bb][n][0];
            f16x4 vi = *(const f16x4*)&yn[j4];
            f16x4 vf = *(const f16x4*)&yn[32 + j4];
            f16x4 vg = *(const f16x4*)&yn[64 + j4];
            f16x4 vo = *(const f16x4*)&yn[96 + j4];
#pragma unroll
            for (int u = 0; u < 4; u++) {
                gi[u] += g * (float)vi[u];
                gf[u] += g * (float)vf[u];
                gg[u] += g * (float)vg[u];
                go[u] += g * (float)vo[u];
            }
        }
        const size_t row = (size_t)(b0 + bb) * Nn + m;
        const int col = jt + j4;
        float cv[4];
        *(float4*)cv = *(const float4*)&c1[row * 128 + col];
        f16x4 ha;
#pragma unroll
        for (int u = 0; u < 4; u++) {
            float si = 1.f / (1.f + expf(-gi[u]));
            float sf = 1.f / (1.f + expf(-gf[u]));
            float so = 1.f / (1.f + expf(-go[u]));
            float cn = sf * cv[u] + si * tanhf(gg[u]);
            cv[u] = cn;
            ha[u] = (f16)(so * tanhf(cn));
        }
        *(float4*)&c1[row * 128 + col] = *(float4*)cv;
        *(f16x4*)&l2cat[row * 320 + col] = ha;
    }
}

// ---------------------------------------------------------------------------
// mix2: G-mix ypB[0:512) + LSTM2, one block per b. h2 -> l2cat[128:256),
// tanh(h2) -> yib.
// ---------------------------------------------------------------------------
__global__ __launch_bounds__(256) void mix2(
    const f16* __restrict__ ypB, const float* __restrict__ G,
    float* __restrict__ c, f16* __restrict__ l2cat, f16* __restrict__ yib)
{
    const int b = blockIdx.x;
    const int tid = threadIdx.x;
    __shared__ __attribute__((aligned(16))) f16 sY[12288];
    __shared__ float sG[576];
    for (int i = tid; i < 576; i += 256) sG[i] = G[i];
    for (int i = tid; i < 1536; i += 256) {
        int n = i >> 6, c8 = (i & 63) * 8;
        *(f16x8*)&sY[n * 512 + c8] = *(const f16x8*)&ypB[((size_t)b * Nn + n) * 1024 + c8];
    }
    __syncthreads();
    for (int w = tid; w < 768; w += 256) {
        const int m = w >> 5, j4 = (w & 31) * 4;
        float gi[4] = {}, gf[4] = {}, gg[4] = {}, go[4] = {};
        const float* gr = &sG[m * 24];
#pragma unroll
        for (int n = 0; n < 24; n++) {
            float g = gr[n];
            const f16* yn = &sY[n * 512];
            f16x4 vi = *(const f16x4*)&yn[j4];
            f16x4 vf = *(const f16x4*)&yn[128 + j4];
            f16x4 vg = *(const f16x4*)&yn[256 + j4];
            f16x4 vo = *(const f16x4*)&yn[384 + j4];
#pragma unroll
            for (int u = 0; u < 4; u++) {
                gi[u] += g * (float)vi[u];
                gf[u] += g * (float)vf[u];
                gg[u] += g * (float)vg[u];
                go[u] += g * (float)vo[u];
            }
        }
        const size_t row = (size_t)b * Nn + m;
        float cv[4];
        *(float4*)cv = *(const float4*)&c[row * 128 + j4];
        f16x4 ha, hb;
#pragma unroll
        for (int u = 0; u < 4; u++) {
            float si = 1.f / (1.f + expf(-gi[u]));
            float sf = 1.f / (1.f + expf(-gf[u]));
            float so = 1.f / (1.f + expf(-go[u]));
            float cn = sf * cv[u] + si * tanhf(gg[u]);
            cv[u] = cn;
            float h = so * tanhf(cn);
            ha[u] = (f16)h;
            hb[u] = (f16)tanhf(h);
        }
        *(float4*)&c[row * 128 + j4] = *(float4*)cv;
        *(f16x4*)&l2cat[row * 320 + 128 + j4] = ha;
        *(f16x4*)&yib[row * 128 + j4] = hb;
    }
}

// ---------------------------------------------------------------------------
// finstep: fc-mix + tanh, heads, second mix, quaternion, outputs, v8f(t+1).
// ---------------------------------------------------------------------------
__global__ __launch_bounds__(256) void finstep(
    const f16* __restrict__ p, const float* __restrict__ G,
    const float* __restrict__ locW, const float* __restrict__ locb,
    const float* __restrict__ lzW, const float* __restrict__ lzb,
    float* __restrict__ ls, f16* __restrict__ v8f,
    float* __restrict__ out, int t)
{
    const int b = blockIdx.x;
    const int tid = threadIdx.x;
    __shared__ __attribute__((aligned(16))) f16 sP[6144];
    __shared__ __attribute__((aligned(16))) f16 sY1[3072], sY2[3072];
    __shared__ float sG[576];
    __shared__ float sLp[24][3], sZp[24][4], sL3[24][3], sZ3[24][4];
    for (int i = tid; i < 576; i += 256) sG[i] = G[i];
    for (int i = tid; i < 768; i += 256) {
        int n = i >> 5, c8 = (i & 31) * 8;
        *(f16x8*)&sP[n * 256 + c8] = *(const f16x8*)&p[((size_t)b * Nn + n) * 256 + c8];
    }
    __syncthreads();
    for (int w = tid; w < 768; w += 256) {
        const int m = w >> 5, o4 = (w & 31) * 4;
        float a1[4] = {}, a2[4] = {};
        const float* gr = &sG[m * 24];
#pragma unroll
        for (int n = 0; n < 24; n++) {
            float g = gr[n];
            f16x4 p1 = *(const f16x4*)&sP[n * 256 + o4];
            f16x4 p2 = *(const f16x4*)&sP[n * 256 + 128 + o4];
#pragma unroll
            for (int u = 0; u < 4; u++) { a1[u] += g * (float)p1[u]; a2[u] += g * (float)p2[u]; }
        }
        f16x4 y1, y2;
#pragma unroll
        for (int u = 0; u < 4; u++) { y1[u] = (f16)tanhf(a1[u]); y2[u] = (f16)tanhf(a2[u]); }
        *(f16x4*)&sY1[m * 128 + o4] = y1;
        *(f16x4*)&sY2[m * 128 + o4] = y2;
    }
    __syncthreads();
    if (tid < 72) {
        int m = tid / 3, j = tid - m * 3;
        float s = locb[j];
        for (int o = 0; o < 128; o++) s += (float)sY1[m * 128 + o] * locW[o * 3 + j];
        sLp[m][j] = s;
    } else if (tid < 168) {
        int w2 = tid - 72; int m = w2 >> 2, j = w2 & 3;
        float s = lzb[j];
        for (int o = 0; o < 128; o++) s += (float)sY2[m * 128 + o] * lzW[o * 4 + j];
        sZp[m][j] = s;
    }
    __syncthreads();
    if (tid < 72) {
        int m = tid / 3, j = tid - m * 3;
        float s = 0.f;
#pragma unroll
        for (int n = 0; n < 24; n++) s += sG[m * 24 + n] * sLp[n][j];
        sL3[m][j] = s;
    } else if (tid < 168) {
        int w2 = tid - 72; int m = w2 >> 2, j = w2 & 3;
        float s = 0.f;
#pragma unroll
        for (int n = 0; n < 24; n++) s += sG[m * 24 + n] * sZp[n][j];
        sZ3[m][j] = s;
    }
    __syncthreads();
    if (tid < 24) {
        const int m = tid;
        float xx = sL3[m][0], xy = sL3[m][1], xz = sL3[m][2];
        float r = rsqrtf(1.f + xx * xx + xy * xy + xz * xz);
        float dw = r, dx = xx * r, dy = xy * r, dz = xz * r;
        size_t li = ((size_t)b * Nn + m) * 4;
        float qw = ls[li], qx = ls[li + 1], qy = ls[li + 2], qz = ls[li + 3];
        float lw = qw * dw - qx * dx - qy * dy - qz * dz;
        float lx = qw * dx + qx * dw + qy * dz - qz * dy;
        float ly = qw * dy - qx * dz + qy * dw + qz * dx;
        float lz = qw * dz + qx * dy - qy * dx + qz * dw;
        size_t oi = (((size_t)b * Tt + t) * Nn + m) * 4;
        out[oi + 0] = lw; out[oi + 1] = lx; out[oi + 2] = ly; out[oi + 3] = lz;
        size_t zi = (size_t)Bsz * Tt * Nn * 4 + oi;
        out[zi + 0] = sZ3[m][0]; out[zi + 1] = sZ3[m][1];
        out[zi + 2] = sZ3[m][2]; out[zi + 3] = sZ3[m][3];
        ls[li] = lw; ls[li + 1] = lx; ls[li + 2] = ly; ls[li + 3] = lz;
        f16x8 v8;
        v8[0] = (f16)lw; v8[1] = (f16)lx; v8[2] = (f16)ly; v8[3] = (f16)lz;
        v8[4] = (f16)dw; v8[5] = (f16)dx; v8[6] = (f16)dy; v8[7] = (f16)dz;
        *(f16x8*)&v8f[((size_t)b * Nn + m) * 8] = v8;
    }
}

extern "C" void kernel_launch(void* const* d_in, const int* in_sizes, int n_in,
                              void* d_out, int out_size, void* d_ws, size_t ws_size,
                              hipStream_t stream)
{
    const float* x    = (const float*)d_in[0];
    const float* enc  = (const float*)d_in[1];
    const float* z    = (const float*)d_in[2];
    const float* G    = (const float*)d_in[4];
    const float* Wx0  = (const float*)d_in[5];
    const float* Wh0  = (const float*)d_in[6];
    const float* b0i  = (const float*)d_in[7];
    const float* Wx1  = (const float*)d_in[8];
    const float* Wh1  = (const float*)d_in[9];
    const float* b1i  = (const float*)d_in[10];
    const float* fcW  = (const float*)d_in[11];
    const float* fcb  = (const float*)d_in[12];
    const float* fc2W = (const float*)d_in[13];
    const float* fc2b = (const float*)d_in[14];
    const float* ih1W = (const float*)d_in[15];
    const float* ih1b = (const float*)d_in[16];
    const float* ih2W = (const float*)d_in[17];
    const float* ih2b = (const float*)d_in[18];
    const float* locW = (const float*)d_in[19];
    const float* locb = (const float*)d_in[20];
    const float* lzW  = (const float*)d_in[21];
    const float* lzb  = (const float*)d_in[22];
    float* out = (float*)d_out;

    const size_t BN = (size_t)Bsz * Nn;
    char* wp = (char*)d_ws;
    size_t off = 0;
    auto carve = [&](size_t bytes) -> char* {
        char* pc = wp + off;
        off += (bytes + 255) & ~(size_t)255;
        return pc;
    };
    f16*   W2ext  = (f16*)carve((size_t)Nn * 1024 * 320 * 2);
    f16*   W8     = (f16*)carve((size_t)Nn * 8 * 512 * 2);
    f16*   Wtf    = (f16*)carve((size_t)Nn * 256 * 128 * 2);
    f16*   Wti    = (f16*)carve((size_t)256 * 256 * 2);
    float* bcat   = (float*)carve((size_t)Nn * 256 * 4);
    float* bcat2  = (float*)carve((size_t)Nn * 1024 * 4);
    float* bi     = (float*)carve(256 * 4);
    f16*   l2cat  = (f16*)carve(BN * 320 * 2);
    f16*   yib    = (f16*)carve(BN * 128 * 2);
    float* c1     = (float*)carve(BN * 128 * 4);
    float* c2     = (float*)carve(BN * 128 * 4);
    float* ls     = (float*)carve(BN * 4 * 4);
    f16*   v8f    = (f16*)carve(BN * 8 * 2);
    f16*   ypB    = (f16*)carve(BN * 1024 * 2);
    f16*   yp0    = (f16*)carve(BN * 256 * 2);
    f16*   pbuf   = (f16*)carve(BN * 256 * 2);

    // ---- one-time prep (tiled transposes: coalesced both sides) ----
    prep_w2ext<<<1920, 256, 0, stream>>>(Wx0, Wh0, Wx1, Wh1, W2ext);
    prep_wtf<<<192, 256, 0, stream>>>(fcW, fc2W, Wtf);
    prep_small<<<384, 256, 0, stream>>>(Wx0, ih1W, ih2W, ih1b, ih2b, fcb, fc2b,
                                        b0i, b1i, W8, Wti, bi, bcat, bcat2);
    init_zl<<<3072, 256, 0, stream>>>(x, z, l2cat, v8f, ls);

    // [h0|c0]pre from enc (fp32 A path): otiles=2, bpn=8, grid 192
    gemm128<<<192, 256, 0, stream>>>(nullptr, enc, 256, Wti, 0, 2, 8, 0,
                                     bi, 0, yp0, 256);
    mix_init<<<512, 256, 0, stream>>>(yp0, G, l2cat, c1, c2);
    // gates1(0)-pre (minus v8 term) = h0*Wh0 + z*Wz + b0 -> ypB[...,512:1024)
    // (l2cat h1-slot currently holds h0). obase=512, otiles=4, bpn=16, grid 384.
    gemm128<<<384, 256, 0, stream>>>(l2cat, nullptr, 320, W2ext, (size_t)1024 * 320,
                                     4, 16, 512, bcat2, 1024, ypB, 1024);

    // ---- T sequential steps: 5 kernels each ----
    for (int t = 0; t < Tt; t++) {
        mix1c<<<256, 256, 0, stream>>>(ypB, W8, v8f, G, c1, l2cat);
        // gemm2ext: O=1024 -> otiles=8, bpn=32, grid 768
        gemm128<<<768, 256, 0, stream>>>(l2cat, nullptr, 320, W2ext, (size_t)1024 * 320,
                                         8, 32, 0, bcat2, 1024, ypB, 1024);
        mix2<<<512, 256, 0, stream>>>(ypB, G, c2, l2cat, yib);
        // gemmf: O=256 -> otiles=2, bpn=8, grid 192
        gemm128<<<192, 256, 0, stream>>>(yib, nullptr, 128, Wtf, (size_t)256 * 128,
                                         2, 8, 0, bcat, 256, pbuf, 256);
        finstep<<<512, 256, 0, stream>>>(pbuf, G, locW, locb, lzW, lzb, ls, v8f, out, t);
    }
}